// Round 8
// baseline (2153.813 us; speedup 1.0000x reference)
//
#include <hip/hip_runtime.h>
#include <hip/hip_bf16.h>

typedef __hip_bfloat16 bf16;
typedef short bf16x8 __attribute__((ext_vector_type(8)));
typedef float f32x4 __attribute__((ext_vector_type(4)));

#define NTOK 16384   // 16*64*16 tokens
#define EDIM 512
#define FFDIM 2048
#define PDIM 768

#define VMCNT(n) asm volatile("s_waitcnt vmcnt(" #n ")")

__device__ __forceinline__ short f2bf(float f) {   // RNE float->bf16 bits
  unsigned u = __float_as_uint(f);
  unsigned r = (u + 0x7fff + ((u >> 16) & 1)) >> 16;
  return (short)r;
}
__device__ __forceinline__ float bf2f(short b) {
  return __uint_as_float(((unsigned)(unsigned short)b) << 16);
}

// async global->LDS DMA, 16B per lane. LDS dest must be linear in lane order.
typedef __attribute__((address_space(3))) unsigned int lds_uint;
typedef __attribute__((address_space(1))) const unsigned int glob_uint;
__device__ __forceinline__ void gl_lds16(const bf16* g, bf16* l) {
  __builtin_amdgcn_global_load_lds((glob_uint*)g, (lds_uint*)l, 16, 0, 0);
}

// ======== weight transpose: fp32 [B][R][C] -> bf16 [B][C][R] ========
__global__ void k_transpose(const float* __restrict__ src, bf16* __restrict__ dst,
                            int R, int C, long srcBS, long dstBS) {
  __shared__ float tile[32][33];
  src += (long)blockIdx.z * srcBS;
  dst += (long)blockIdx.z * dstBS;
  int c0 = blockIdx.x * 32, r0 = blockIdx.y * 32;
  int tx = threadIdx.x, ty = threadIdx.y;
#pragma unroll
  for (int j = ty; j < 32; j += 8)
    tile[j][tx] = src[(long)(r0 + j) * C + (c0 + tx)];
  __syncthreads();
#pragma unroll
  for (int j = ty; j < 32; j += 8)
    dst[(long)(c0 + j) * R + (r0 + tx)] = __float2bfloat16(tile[tx][j]);
}

// ======== pack QKV biases -> [2][6][1536] fp32 ========
__global__ void k_pack_bias(const float* __restrict__ sq, const float* __restrict__ sk,
                            const float* __restrict__ sv, const float* __restrict__ tq,
                            const float* __restrict__ tk, const float* __restrict__ tv,
                            float* __restrict__ dst) {
  int i = blockIdx.x * 256 + threadIdx.x;
  if (i >= 2 * 6 * 1536) return;
  int pre = i / (6 * 1536), rem = i % (6 * 1536), l = rem / 1536, e = rem % 1536;
  const float* s;
  if (pre == 0) s = (e < 512) ? sq : (e < 1024) ? sk : sv;
  else          s = (e < 512) ? tq : (e < 1024) ? tk : tv;
  dst[i] = s[l * 512 + (e & 511)];
}

// ======== patchify: frames fp32 [16][64][3][64][64] -> P bf16 [16384][768] ========
__global__ void k_patchify(const float* __restrict__ frames, bf16* __restrict__ P) {
  int gid = blockIdx.x * 256 + threadIdx.x;           // < 16384*96
  int token = gid / 96, chunk = gid % 96;
  int b = token >> 10, s = (token >> 4) & 63, p = token & 15;
  int c = chunk >> 5, rem = chunk & 31, p1 = rem >> 1, p2b = (rem & 1) * 8;
  int h = p >> 2, w = p & 3;
  const float* src = frames + ((long)(((b * 64 + s) * 3 + c) * 64 + h * 16 + p1)) * 64 + w * 16 + p2b;
  float4 f0 = *reinterpret_cast<const float4*>(src);
  float4 f1 = *reinterpret_cast<const float4*>(src + 4);
  bf16* dst = P + (long)token * PDIM + chunk * 8;
  dst[0] = __float2bfloat16(f0.x); dst[1] = __float2bfloat16(f0.y);
  dst[2] = __float2bfloat16(f0.z); dst[3] = __float2bfloat16(f0.w);
  dst[4] = __float2bfloat16(f1.x); dst[5] = __float2bfloat16(f1.y);
  dst[6] = __float2bfloat16(f1.z); dst[7] = __float2bfloat16(f1.w);
}

// ======== MFMA GEMM, BK=64 2-deep counted-vmcnt pipeline (R7-verified) ========
template <int RELU, int RES, int POS, int WF, int WB>
__global__ __launch_bounds__(256, 2) void k_gemm(
    const bf16* __restrict__ A, const bf16* __restrict__ WT,
    const float* __restrict__ bias, const float* __restrict__ res,
    const float* __restrict__ pos, float* __restrict__ outF, bf16* __restrict__ outB,
    int N, int K, int nwgx) {
  __shared__ bf16 As[2][128 * 64];
  __shared__ bf16 Bs[2][128 * 64];
  int tid = threadIdx.x;
  int wave = tid >> 6, lane = tid & 63;
  int wm = wave >> 1, wn = wave & 1;
  int nwg = gridDim.x;
  int id = blockIdx.x;
  int sw = (id & 7) * (nwg >> 3) + (id >> 3);
  int m0 = (sw / nwgx) * 128, n0 = (sw % nwgx) * 128;
  f32x4 acc[4][4] = {};
  int lrow = lane & 15;
  int rs_ = tid >> 3, js = tid & 7;
  int gc = (js ^ (rs_ & 7)) * 8;
  int e = tid * 8;
  int kq = lane >> 4;

  auto STAGE = [&](int buf, int k0) {
#pragma unroll
    for (int q = 0; q < 4; q++)
      gl_lds16(&A [(long)(m0 + q * 32 + rs_) * K + k0 + gc], &As[buf][q * 2048 + e]);
#pragma unroll
    for (int q = 0; q < 4; q++)
      gl_lds16(&WT[(long)(n0 + q * 32 + rs_) * K + k0 + gc], &Bs[buf][q * 2048 + e]);
  };

  int nIter = K >> 6;
  STAGE(0, 0); STAGE(1, 64);
  int cur = 0;
  for (int it = 0; it < nIter; ++it) {
    if (it + 1 < nIter) VMCNT(8);
    else               VMCNT(0);
    __builtin_amdgcn_s_barrier();
    bf16x8 af[2][4], bfr[2][4];
#pragma unroll
    for (int s = 0; s < 2; s++) {
      int kc = ((s * 4 + kq) ^ (lrow & 7)) * 8;
#pragma unroll
      for (int i = 0; i < 4; i++) {
        af[s][i]  = *reinterpret_cast<const bf16x8*>(&As[cur][(wm * 64 + i * 16 + lrow) * 64 + kc]);
        bfr[s][i] = *reinterpret_cast<const bf16x8*>(&Bs[cur][(wn * 64 + i * 16 + lrow) * 64 + kc]);
      }
    }
    asm volatile("s_waitcnt lgkmcnt(0)");
    __builtin_amdgcn_sched_barrier(0);
    __builtin_amdgcn_s_barrier();
    if (it + 2 < nIter) STAGE(cur, (it + 2) << 6);
    __builtin_amdgcn_s_setprio(1);
#pragma unroll
    for (int s = 0; s < 2; s++)
#pragma unroll
      for (int i = 0; i < 4; i++)
#pragma unroll
        for (int j = 0; j < 4; j++)
          acc[i][j] = __builtin_amdgcn_mfma_f32_16x16x32_bf16(af[s][i], bfr[s][j], acc[i][j], 0, 0, 0);
    __builtin_amdgcn_s_setprio(0);
    cur ^= 1;
  }
  int rq = lane >> 4;
#pragma unroll
  for (int i = 0; i < 4; i++) {
#pragma unroll
    for (int j = 0; j < 4; j++) {
      int col = n0 + wn * 64 + j * 16 + lrow;
      float bv = bias[col];
#pragma unroll
      for (int rr = 0; rr < 4; rr++) {
        int rowg = m0 + wm * 64 + i * 16 + rq * 4 + rr;
        float v = acc[i][j][rr] + bv;
        if (POS) v += pos[(rowg & 15) * EDIM + col];
        if (RES) v += res[(long)rowg * N + col];
        if (RELU) v = fmaxf(v, 0.f);
        if (WF) outF[(long)rowg * N + col] = v;
        if (WB) outB[(long)rowg * N + col] = __float2bfloat16(v);
      }
    }
  }
}

// ======== fused GEMM(N=512,K=512) + bias + residual + LayerNorm ========
// BM=32, BN=512 (full rows per block), BK=32, 256 thr (4 waves: 2 wm x 2 wn).
// Frag-contiguous LDS: 1KB segment s holds rows 16s..16s+15 at offset
// (kc*16 + (row&15))*16B; MFMA frag read = seg_base + lane*16 (stride-1,
// conflict-free). Global src per-lane chosen so 64B lines fully consumed.
// Counted vmcnt(9) 2-deep pipeline. LN: 16-lane shfl + cross-wn LDS combine.
// In-place res=xf read -> xf write (rows disjoint across blocks).
__global__ __launch_bounds__(256, 2) void k_gemm_ln(
    const bf16* __restrict__ A, const bf16* __restrict__ WT,
    const float* __restrict__ bias, const float* __restrict__ res,
    const float* __restrict__ g, const float* __restrict__ bet,
    float* __restrict__ xf, bf16* __restrict__ xb, int K) {
  __shared__ bf16 Bs[2][512 * 32];   // 32 segs x 512 elem
  __shared__ bf16 As[2][32 * 32];    // 2 segs x 512 elem
  __shared__ float stats[2][32][2];
  int tid = threadIdx.x;
  int wave = tid >> 6, lane = tid & 63;
  int wm = wave >> 1, wn = wave & 1;
  int nwg = gridDim.x;
  int id = blockIdx.x;
  int sw = (id & 7) * (nwg >> 3) + (id >> 3);
  int m0 = sw * 32;
  int lrow = lane & 15, rq = lane >> 4;
  // staging decode: B issue i covers segs i*4+(t>>6); within seg: kc=(t>>4)&3, r=t&15
  int sLr = tid & 15, sKc = (tid >> 4) & 3, sSeg4 = tid >> 6;
  int tA = tid & 127;
  int aLr = tA & 15, aKc = (tA >> 4) & 3, aSeg = tA >> 6;

  auto STAGE = [&](int buf, int k0) {
#pragma unroll
    for (int i = 0; i < 8; i++)
      gl_lds16(&WT[(long)((i * 4 + sSeg4) * 16 + sLr) * K + k0 + sKc * 8],
               &Bs[buf][i * 2048 + tid * 8]);
    // A: 2KB staged by lower 128 lane-slots; upper half duplicates (benign,
    // keeps per-wave vmcnt uniform at 9)
    gl_lds16(&A[(long)(m0 + aSeg * 16 + aLr) * K + k0 + aKc * 8],
             &As[buf][tA * 8]);
  };

  f32x4 acc[16] = {};
  int nIter = K >> 5;                        // K=512 -> 16
  STAGE(0, 0); STAGE(1, 32);
  int cur = 0;
  for (int it = 0; it < nIter; ++it) {
    if (it + 1 < nIter) VMCNT(9);
    else               VMCNT(0);
    __builtin_amdgcn_s_barrier();
    bf16x8 af = *reinterpret_cast<const bf16x8*>(&As[cur][wm * 512 + lane * 8]);
    bf16x8 bfr[16];
#pragma unroll
    for (int j = 0; j < 16; j++)
      bfr[j] = *reinterpret_cast<const bf16x8*>(&Bs[cur][(wn * 16 + j) * 512 + lane * 8]);
    asm volatile("s_waitcnt lgkmcnt(0)");
    __builtin_amdgcn_sched_barrier(0);
    __builtin_amdgcn_s_barrier();
    if (it + 2 < nIter) STAGE(cur, (it + 2) << 5);
    __builtin_amdgcn_s_setprio(1);
#pragma unroll
    for (int j = 0; j < 16; j++)
      acc[j] = __builtin_amdgcn_mfma_f32_16x16x32_bf16(af, bfr[j], acc[j], 0, 0, 0);
    __builtin_amdgcn_s_setprio(0);
    cur ^= 1;
  }

  // epilogue: t = acc + bias + res; LN over 512 cols
  float s[4] = {}, q2[4] = {};
#pragma unroll
  for (int j = 0; j < 16; j++) {
    int col = wn * 256 + j * 16 + lrow;
    float bv = bias[col];
#pragma unroll
    for (int rr = 0; rr < 4; rr++) {
      int rowg = m0 + wm * 16 + rq * 4 + rr;
      float v = acc[j][rr] + bv + res[(long)rowg * EDIM + col];
      acc[j][rr] = v;
      s[rr] += v; q2[rr] += v * v;
    }
  }
#pragma unroll
  for (int off = 1; off < 16; off <<= 1)
#pragma unroll
    for (int rr = 0; rr < 4; rr++) {
      s[rr] += __shfl_xor(s[rr], off);
      q2[rr] += __shfl_xor(q2[rr], off);
    }
  if (lrow == 0) {
#pragma unroll
    for (int rr = 0; rr < 4; rr++) {
      int rloc = wm * 16 + rq * 4 + rr;
      stats[wn][rloc][0] = s[rr];
      stats[wn][rloc][1] = q2[rr];
    }
  }
  __syncthreads();
  float mean_[4], rs_[4];
#pragma unroll
  for (int rr = 0; rr < 4; rr++) {
    int rloc = wm * 16 + rq * 4 + rr;
    float S = stats[0][rloc][0] + stats[1][rloc][0];
    float Q = stats[0][rloc][1] + stats[1][rloc][1];
    float mn = S * (1.f / 512.f);
    mean_[rr] = mn;
    rs_[rr] = rsqrtf(Q * (1.f / 512.f) - mn * mn + 1e-5f);
  }
#pragma unroll
  for (int j = 0; j < 16; j++) {
    int col = wn * 256 + j * 16 + lrow;
    float gg = g[col], bb = bet[col];
#pragma unroll
    for (int rr = 0; rr < 4; rr++) {
      int rowg = m0 + wm * 16 + rq * 4 + rr;
      float y = (acc[j][rr] - mean_[rr]) * rs_[rr] * gg + bb;
      xf[(long)rowg * EDIM + col] = y;
      xb[(long)rowg * EDIM + col] = __float2bfloat16(y);
    }
  }
}

// ======== spatial attention: 1 wave per (b*s, head); 16 patches, d=64 ========
__global__ __launch_bounds__(64) void k_attn_spatial(const bf16* __restrict__ qkv,
                                                     bf16* __restrict__ o) {
  __shared__ float qs[16][68], ks[16][68], vs[16][68], sc[16][17];
  int bs = blockIdx.x >> 3, h = blockIdx.x & 7;
  int lane = threadIdx.x;
  int R0 = bs * 16;
  int row = lane >> 2, d0 = (lane & 3) * 16;
  const bf16* bse = qkv + (long)(R0 + row) * 1536 + h * 64 + d0;
#pragma unroll
  for (int u = 0; u < 2; u++) {
    bf16x8 aq = *reinterpret_cast<const bf16x8*>(bse + u * 8);
    bf16x8 ak = *reinterpret_cast<const bf16x8*>(bse + 512 + u * 8);
    bf16x8 av = *reinterpret_cast<const bf16x8*>(bse + 1024 + u * 8);
#pragma unroll
    for (int e = 0; e < 8; e++) {
      qs[row][d0 + u * 8 + e] = bf2f(aq[e]);
      ks[row][d0 + u * 8 + e] = bf2f(ak[e]);
      vs[row][d0 + u * 8 + e] = bf2f(av[e]);
    }
  }
  __syncthreads();
  int i = lane >> 2, j0 = (lane & 3) * 4;
  for (int j = j0; j < j0 + 4; j++) {
    float d = 0.f;
    for (int kk = 0; kk < 64; kk++) d += qs[i][kk] * ks[j][kk];
    sc[i][j] = d * 0.125f;
  }
  __syncthreads();
  if (lane < 16) {
    float m = -1e30f;
    for (int j = 0; j < 16; j++) m = fmaxf(m, sc[lane][j]);
    float ssum = 0.f;
    for (int j = 0; j < 16; j++) { float e = __expf(sc[lane][j] - m); sc[lane][j] = e; ssum += e; }
    float inv = 1.f / ssum;
    for (int j = 0; j < 16; j++) sc[lane][j] *= inv;
  }
  __syncthreads();
  int dq = lane & 3;
  for (int dd = dq * 16; dd < dq * 16 + 16; dd++) {
    float acc = 0.f;
    for (int j = 0; j < 16; j++) acc += sc[i][j] * vs[j][dd];
    o[(long)(R0 + i) * EDIM + h * 64 + dd] = __float2bfloat16(acc);
  }
}

// ======== temporal causal attention, MFMA: 1 wave per (b, p, h); S=64, D=64 ====
__global__ __launch_bounds__(64) void k_attn_temporal_mfma(const bf16* __restrict__ qkv,
                                                           bf16* __restrict__ o) {
  __shared__ short Plds[64 * 72];
  __shared__ short VT[64 * 72];
  int bp = blockIdx.x >> 3, h = blockIdx.x & 7;
  int b = bp >> 4, p = bp & 15;
  int lane = threadIdx.x;
  int c = lane & 15, q = lane >> 4;
  const long RSTR = 16 * 1536;
  const bf16* qb = qkv + ((long)(b * 1024 + p)) * 1536 + h * 64;

  {
    bf16x8 z = {};
#pragma unroll
    for (int t = 0; t < 9; t++)
      *reinterpret_cast<bf16x8*>(&Plds[(t * 64 + lane) * 8]) = z;
  }
#pragma unroll
  for (int t = 0; t < 8; t++) {
    int s = t * 8 + (lane >> 3), d0 = (lane & 7) * 8;
    bf16x8 v = *reinterpret_cast<const bf16x8*>(qb + 1024 + (long)s * RSTR + d0);
#pragma unroll
    for (int u = 0; u < 8; u++) {
      int d = d0 + u;
      VT[d * 72 + (s ^ (((d >> 3) & 7) << 3))] = v[u];
    }
  }
  __syncthreads();

  f32x4 sAcc[4][4] = {};
#pragma unroll
  for (int ks = 0; ks < 2; ks++) {
    bf16x8 kf[4];
#pragma unroll
    for (int j = 0; j < 4; j++)
      kf[j] = *reinterpret_cast<const bf16x8*>(qb + 512 + (long)(16 * j + c) * RSTR + 32 * ks + 8 * q);
#pragma unroll
    for (int i = 0; i < 4; i++) {
      bf16x8 qf = *reinterpret_cast<const bf16x8*>(qb + (long)(16 * i + c) * RSTR + 32 * ks + 8 * q);
#pragma unroll
      for (int j = 0; j < 4; j++)
        if (j <= i)
          sAcc[i][j] = __builtin_amdgcn_mfma_f32_16x16x32_bf16(qf, kf[j], sAcc[i][j], 0, 0, 0);
    }
  }

  f32x4 invs[4];
#pragma unroll
  for (int i = 0; i < 4; i++) {
    f32x4 mx;
#pragma unroll
    for (int r = 0; r < 4; r++) mx[r] = -1e30f;
#pragma unroll
    for (int j = 0; j <= i; j++)
#pragma unroll
      for (int r = 0; r < 4; r++) {
        float v = sAcc[i][j][r] * 0.125f;
        if (j == i && c > 4 * q + r) v = -1e30f;
        sAcc[i][j][r] = v;
        mx[r] = fmaxf(mx[r], v);
      }
#pragma unroll
    for (int off = 1; off < 16; off <<= 1)
#pragma unroll
      for (int r = 0; r < 4; r++) mx[r] = fmaxf(mx[r], __shfl_xor(mx[r], off));
    f32x4 sm = {};
#pragma unroll
    for (int j = 0; j <= i; j++)
#pragma unroll
      for (int r = 0; r < 4; r++) {
        float e = __expf(sAcc[i][j][r] - mx[r]);
        sm[r] += e;
        Plds[(16 * i + 4 * q + r) * 72 + 16 * j + c] = f2bf(e);
      }
#pragma unroll
    for (int off = 1; off < 16; off <<= 1)
#pragma unroll
      for (int r = 0; r < 4; r++) sm[r] += __shfl_xor(sm[r], off);
#pragma unroll
    for (int r = 0; r < 4; r++) invs[i][r] = 1.f / sm[r];
  }
  __syncthreads();

  f32x4 oacc[4][4] = {};
#pragma unroll
  for (int kb = 0; kb < 2; kb++) {
    bf16x8 vb[4];
#pragma unroll
    for (int db = 0; db < 4; db++) {
      int d = 16 * db + c;
      vb[db] = *reinterpret_cast<const bf16x8*>(&VT[d * 72 + ((32 * kb + 8 * q) ^ (((d >> 3) & 7) << 3))]);
    }
#pragma unroll
    for (int i = 0; i < 4; i++) {
      if (kb == 1 && i < 2) continue;
      bf16x8 pa = *reinterpret_cast<const bf16x8*>(&Plds[(16 * i + c) * 72 + 32 * kb + 8 * q]);
#pragma unroll
      for (int db = 0; db < 4; db++)
        oacc[i][db] = __builtin_amdgcn_mfma_f32_16x16x32_bf16(pa, vb[db], oacc[i][db], 0, 0, 0);
    }
  }

#pragma unroll
  for (int i = 0; i < 4; i++)
#pragma unroll
    for (int db = 0; db < 4; db++)
#pragma unroll
      for (int r = 0; r < 4; r++) {
        int srow = 16 * i + 4 * q + r;
        long tok = (long)(b * 64 + srow) * 16 + p;
        o[tok * EDIM + h * 64 + 16 * db + c] = __float2bfloat16(oacc[i][db][r] * invs[i][r]);
      }
}

// ======== LayerNorm over 512: 1 wave per row ========
__global__ __launch_bounds__(64) void k_ln(const float* __restrict__ r,
                                           const float* __restrict__ g,
                                           const float* __restrict__ b,
                                           float* __restrict__ xf,
                                           bf16* __restrict__ xb) {
  int row = blockIdx.x, lane = threadIdx.x;
  const float4* rp = reinterpret_cast<const float4*>(r + (long)row * EDIM);
  float4 a = rp[lane * 2], c = rp[lane * 2 + 1];
  float s = a.x + a.y + a.z + a.w + c.x + c.y + c.z + c.w;
  float q = a.x * a.x + a.y * a.y + a.z * a.z + a.w * a.w +
            c.x * c.x + c.y * c.y + c.z * c.z + c.w * c.w;
#pragma unroll
  for (int off = 32; off; off >>= 1) { s += __shfl_xor(s, off); q += __shfl_xor(q, off); }
  float mean = s * (1.f / EDIM);
  float var = q * (1.f / EDIM) - mean * mean;
  float rs = rsqrtf(var + 1e-5f);
  float vals[8] = {a.x, a.y, a.z, a.w, c.x, c.y, c.z, c.w};
  long base = (long)row * EDIM + lane * 8;
#pragma unroll
  for (int u = 0; u < 8; u++) {
    int cidx = lane * 8 + u;
    float y = (vals[u] - mean) * rs * g[cidx] + b[cidx];
    xf[base + u] = y;
    xb[base + u] = __float2bfloat16(y);
  }
}

// ======== head: pool over patches, pair-concat, LN(1024), @ h_w + h_b ========
__global__ __launch_bounds__(256) void k_head(const float* __restrict__ xf,
                                              const float* __restrict__ g,
                                              const float* __restrict__ b,
                                              const float* __restrict__ hw,
                                              const float* __restrict__ hb,
                                              float* __restrict__ actions) {
  __shared__ float lnv[1024];
  __shared__ float red[10];
  int blk = blockIdx.x;               // 16*63
  int bb = blk / 63, t = blk % 63;
  int tid = threadIdx.x;
  float vals[4];
  float s = 0.f, q = 0.f;
#pragma unroll
  for (int u = 0; u < 4; u++) {
    int idx = tid * 4 + u;            // 0..1023
    int half = idx >> 9, e = idx & 511;
    const float* base = xf + (long)(((bb * 64) + t + half) * 16) * EDIM + e;
    float acc = 0.f;
#pragma unroll
    for (int p = 0; p < 16; p++) acc += base[p * EDIM];
    acc *= (1.f / 16.f);
    vals[u] = acc; s += acc; q += acc * acc;
  }
#pragma unroll
  for (int off = 32; off; off >>= 1) { s += __shfl_xor(s, off); q += __shfl_xor(q, off); }
  if ((tid & 63) == 0) { red[tid >> 6] = s; red[4 + (tid >> 6)] = q; }
  __syncthreads();
  if (tid == 0) {
    float S = red[0] + red[1] + red[2] + red[3];
    float Q = red[4] + red[5] + red[6] + red[7];
    float m = S * (1.f / 1024.f);
    red[8] = m;
    red[9] = rsqrtf(Q * (1.f / 1024.f) - m * m + 1e-5f);
  }
  __syncthreads();
  float m = red[8], rs = red[9];
#pragma unroll
  for (int u = 0; u < 4; u++) {
    int idx = tid * 4 + u;
    lnv[idx] = (vals[u] - m) * rs * g[idx] + b[idx];
  }
  __syncthreads();
  if (tid < 64) {
    float acc = hb[tid];
    for (int e = 0; e < 1024; e++) acc += lnv[e] * hw[e * 64 + tid];
    actions[(long)blk * 64 + tid] = acc;
  }
}

extern "C" void kernel_launch(void* const* d_in, const int* in_sizes, int n_in,
                              void* d_out, int out_size, void* d_ws, size_t ws_size,
                              hipStream_t stream) {
  (void)in_sizes; (void)n_in; (void)out_size; (void)ws_size;
  const float* frames  = (const float*)d_in[0];
  const float* w_patch = (const float*)d_in[1];
  const float* b_patch = (const float*)d_in[2];
  const float* pos     = (const float*)d_in[3];
  const float* s_w[4]  = {(const float*)d_in[4],  (const float*)d_in[5],
                          (const float*)d_in[6],  (const float*)d_in[7]};
  const float* s_bq = (const float*)d_in[8];
  const float* s_bk = (const float*)d_in[9];
  const float* s_bv = (const float*)d_in[10];
  const float* s_bo = (const float*)d_in[11];
  const float* s_lng = (const float*)d_in[12];
  const float* s_lnb = (const float*)d_in[13];
  const float* t_w[4]  = {(const float*)d_in[14], (const float*)d_in[15],
                          (const float*)d_in[16], (const float*)d_in[17]};
  const float* t_bq = (const float*)d_in[18];
  const float* t_bk = (const float*)d_in[19];
  const float* t_bv = (const float*)d_in[20];
  const float* t_bo = (const float*)d_in[21];
  const float* t_lng = (const float*)d_in[22];
  const float* t_lnb = (const float*)d_in[23];
  const float* f_w1 = (const float*)d_in[24];
  const float* f_b1 = (const float*)d_in[25];
  const float* f_w2 = (const float*)d_in[26];
  const float* f_b2 = (const float*)d_in[27];
  const float* f_lng = (const float*)d_in[28];
  const float* f_lnb = (const float*)d_in[29];
  const float* h_lng = (const float*)d_in[30];
  const float* h_lnb = (const float*)d_in[31];
  const float* h_w = (const float*)d_in[32];
  const float* h_b = (const float*)d_in[33];

  char* ws = (char*)d_ws;
  size_t off = 0;
  auto alloc = [&](size_t bytes) { size_t o = off; off += (bytes + 255) & ~(size_t)255; return o; };
  bf16* sqkvT = (bf16*)(ws + alloc((size_t)6 * 1536 * 512 * 2));
  bf16* swoT  = (bf16*)(ws + alloc((size_t)6 * 512 * 512 * 2));
  bf16* tqkvT = (bf16*)(ws + alloc((size_t)6 * 1536 * 512 * 2));
  bf16* twoT  = (bf16*)(ws + alloc((size_t)6 * 512 * 512 * 2));
  bf16* w1T   = (bf16*)(ws + alloc((size_t)6 * 2048 * 512 * 2));
  bf16* w2T   = (bf16*)(ws + alloc((size_t)6 * 512 * 2048 * 2));
  bf16* wpT   = (bf16*)(ws + alloc((size_t)512 * 768 * 2));
  float* bqkv = (float*)(ws + alloc((size_t)2 * 6 * 1536 * 4));
  float* xf   = (float*)(ws + alloc((size_t)NTOK * EDIM * 4));
  bf16* xb    = (bf16*)(ws + alloc((size_t)NTOK * EDIM * 2));
  char* regC  = ws + alloc((size_t)NTOK * 1536 * 2);   // qkv bf16 | r fp32 (phase-disjoint)
  char* regD  = ws + alloc((size_t)NTOK * 2048 * 2);   // P | o | h1 (phase-disjoint)
  bf16* qkv  = (bf16*)regC;
  float* rbuf = (float*)regC;
  bf16* Pmat = (bf16*)regD;
  bf16* obuf = (bf16*)regD;
  bf16* h1   = (bf16*)regD;

  dim3 tb(32, 8);
  for (int pre = 0; pre < 2; pre++) {
    const float* const* wsrc = pre ? t_w : s_w;
    bf16* qdst = pre ? tqkvT : sqkvT;
    bf16* odst = pre ? twoT : swoT;
    for (int wi = 0; wi < 3; wi++)
      k_transpose<<<dim3(16, 16, 6), tb, 0, stream>>>(wsrc[wi], qdst + wi * 512 * 512,
                                                      512, 512, 262144L, 786432L);
    k_transpose<<<dim3(16, 16, 6), tb, 0, stream>>>(wsrc[3], odst, 512, 512, 262144L, 262144L);
  }
  k_transpose<<<dim3(64, 16, 6), tb, 0, stream>>>(f_w1, w1T, 512, 2048, 1048576L, 1048576L);
  k_transpose<<<dim3(16, 64, 6), tb, 0, stream>>>(f_w2, w2T, 2048, 512, 1048576L, 1048576L);
  k_transpose<<<dim3(16, 24, 1), tb, 0, stream>>>(w_patch, wpT, 768, 512, 0L, 0L);
  k_pack_bias<<<72, 256, 0, stream>>>(s_bq, s_bk, s_bv, t_bq, t_bk, t_bv, bqkv);

  k_patchify<<<6144, 256, 0, stream>>>(frames, Pmat);
  // grids: all 1D, count % 8 == 0 (bijective XCD swizzle requirement)
  k_gemm<0, 0, 1, 1, 1><<<512, 256, 0, stream>>>(
      Pmat, wpT, b_patch, nullptr, pos, xf, xb, 512, 768, 4);

  float* out = (float*)d_out;
  float* xf_final = out + 64512;   // second output: x fp32, written by last LN

  for (int l = 0; l < 6; l++) {
    // ---- spatial attention ----
    k_gemm<0, 0, 0, 0, 1><<<1536, 256, 0, stream>>>(
        xb, sqkvT + (size_t)l * 1536 * 512, bqkv + l * 1536,
        nullptr, nullptr, nullptr, qkv, 1536, 512, 12);
    k_attn_spatial<<<8192, 64, 0, stream>>>(qkv, obuf);
    k_gemm_ln<<<512, 256, 0, stream>>>(
        obuf, swoT + (size_t)l * 512 * 512, s_bo + l * 512,
        xf, s_lng + l * 512, s_lnb + l * 512, xf, xb, 512);
    // ---- temporal attention ----
    k_gemm<0, 0, 0, 0, 1><<<1536, 256, 0, stream>>>(
        xb, tqkvT + (size_t)l * 1536 * 512, bqkv + (6 + l) * 1536,
        nullptr, nullptr, nullptr, qkv, 1536, 512, 12);
    k_attn_temporal_mfma<<<2048, 64, 0, stream>>>(qkv, obuf);
    k_gemm_ln<<<512, 256, 0, stream>>>(
        obuf, twoT + (size_t)l * 512 * 512, t_bo + l * 512,
        xf, t_lng + l * 512, t_lnb + l * 512, xf, xb, 512);
    // ---- FFN ----
    k_gemm<1, 0, 0, 0, 1><<<2048, 256, 0, stream>>>(
        xb, w1T + (size_t)l * 2048 * 512, f_b1 + l * 2048,
        nullptr, nullptr, nullptr, h1, 2048, 512, 16);
    k_gemm<0, 1, 0, 1, 0><<<512, 256, 0, stream>>>(
        h1, w2T + (size_t)l * 512 * 2048, f_b2 + l * 512,
        xf, nullptr, rbuf, nullptr, 512, 2048, 4);
    float* xf_out = (l == 5) ? xf_final : xf;
    k_ln<<<NTOK, 64, 0, stream>>>(rbuf, f_lng + l * 512, f_lnb + l * 512, xf_out, xb);
  }

  k_head<<<1008, 256, 0, stream>>>(xf_final, h_lng, h_lnb, h_w, h_b, out);
}

// Round 9
// 1965.764 us; speedup vs baseline: 1.0957x; 1.0957x over previous
//
#include <hip/hip_runtime.h>
#include <hip/hip_bf16.h>

typedef __hip_bfloat16 bf16;
typedef short bf16x8 __attribute__((ext_vector_type(8)));
typedef float f32x4 __attribute__((ext_vector_type(4)));

#define NTOK 16384   // 16*64*16 tokens
#define EDIM 512
#define FFDIM 2048
#define PDIM 768

#define VMCNT(n) asm volatile("s_waitcnt vmcnt(" #n ")")

__device__ __forceinline__ short f2bf(float f) {   // RNE float->bf16 bits
  unsigned u = __float_as_uint(f);
  unsigned r = (u + 0x7fff + ((u >> 16) & 1)) >> 16;
  return (short)r;
}
__device__ __forceinline__ float bf2f(short b) {
  return __uint_as_float(((unsigned)(unsigned short)b) << 16);
}

// async global->LDS DMA, 16B per lane. LDS dest must be linear in lane order.
typedef __attribute__((address_space(3))) unsigned int lds_uint;
typedef __attribute__((address_space(1))) const unsigned int glob_uint;
__device__ __forceinline__ void gl_lds16(const bf16* g, bf16* l) {
  __builtin_amdgcn_global_load_lds((glob_uint*)g, (lds_uint*)l, 16, 0, 0);
}

// ======== weight transpose: fp32 [B][R][C] -> bf16 [B][C][R] ========
__global__ void k_transpose(const float* __restrict__ src, bf16* __restrict__ dst,
                            int R, int C, long srcBS, long dstBS) {
  __shared__ float tile[32][33];
  src += (long)blockIdx.z * srcBS;
  dst += (long)blockIdx.z * dstBS;
  int c0 = blockIdx.x * 32, r0 = blockIdx.y * 32;
  int tx = threadIdx.x, ty = threadIdx.y;
#pragma unroll
  for (int j = ty; j < 32; j += 8)
    tile[j][tx] = src[(long)(r0 + j) * C + (c0 + tx)];
  __syncthreads();
#pragma unroll
  for (int j = ty; j < 32; j += 8)
    dst[(long)(c0 + j) * R + (r0 + tx)] = __float2bfloat16(tile[tx][j]);
}

// ======== pack QKV biases -> [2][6][1536] fp32 ========
__global__ void k_pack_bias(const float* __restrict__ sq, const float* __restrict__ sk,
                            const float* __restrict__ sv, const float* __restrict__ tq,
                            const float* __restrict__ tk, const float* __restrict__ tv,
                            float* __restrict__ dst) {
  int i = blockIdx.x * 256 + threadIdx.x;
  if (i >= 2 * 6 * 1536) return;
  int pre = i / (6 * 1536), rem = i % (6 * 1536), l = rem / 1536, e = rem % 1536;
  const float* s;
  if (pre == 0) s = (e < 512) ? sq : (e < 1024) ? sk : sv;
  else          s = (e < 512) ? tq : (e < 1024) ? tk : tv;
  dst[i] = s[l * 512 + (e & 511)];
}

// ======== patchify: frames fp32 [16][64][3][64][64] -> P bf16 [16384][768] ========
__global__ void k_patchify(const float* __restrict__ frames, bf16* __restrict__ P) {
  int gid = blockIdx.x * 256 + threadIdx.x;           // < 16384*96
  int token = gid / 96, chunk = gid % 96;
  int b = token >> 10, s = (token >> 4) & 63, p = token & 15;
  int c = chunk >> 5, rem = chunk & 31, p1 = rem >> 1, p2b = (rem & 1) * 8;
  int h = p >> 2, w = p & 3;
  const float* src = frames + ((long)(((b * 64 + s) * 3 + c) * 64 + h * 16 + p1)) * 64 + w * 16 + p2b;
  float4 f0 = *reinterpret_cast<const float4*>(src);
  float4 f1 = *reinterpret_cast<const float4*>(src + 4);
  bf16* dst = P + (long)token * PDIM + chunk * 8;
  dst[0] = __float2bfloat16(f0.x); dst[1] = __float2bfloat16(f0.y);
  dst[2] = __float2bfloat16(f0.z); dst[3] = __float2bfloat16(f0.w);
  dst[4] = __float2bfloat16(f1.x); dst[5] = __float2bfloat16(f1.y);
  dst[6] = __float2bfloat16(f1.z); dst[7] = __float2bfloat16(f1.w);
}

// ======== MFMA GEMM, BK=64 2-deep counted-vmcnt + split-lgkmcnt pipeline ======
// 128x128 tile, BK=64, 4 waves (2x2). Double-buffered global_load_lds staging,
// counted vmcnt(8) across barriers (R7-verified). NEW: intra-iter lgkmcnt(8)
// split — s=0 MFMA cluster overlaps s=1 ds_reads (per-wave only; barrier
// placement and drain guarantees identical to R7).
template <int RELU, int RES, int POS, int WF, int WB>
__global__ __launch_bounds__(256, 2) void k_gemm(
    const bf16* __restrict__ A, const bf16* __restrict__ WT,
    const float* __restrict__ bias, const float* __restrict__ res,
    const float* __restrict__ pos, float* __restrict__ outF, bf16* __restrict__ outB,
    int N, int K, int nwgx) {
  __shared__ bf16 As[2][128 * 64];
  __shared__ bf16 Bs[2][128 * 64];
  int tid = threadIdx.x;
  int wave = tid >> 6, lane = tid & 63;
  int wm = wave >> 1, wn = wave & 1;
  // XCD-aware bijective swizzle: consecutive tiles -> same XCD chunk
  int nwg = gridDim.x;
  int id = blockIdx.x;
  int sw = (id & 7) * (nwg >> 3) + (id >> 3);
  int m0 = (sw / nwgx) * 128, n0 = (sw % nwgx) * 128;
  f32x4 acc[4][4] = {};
  int lrow = lane & 15;
  int rs_ = tid >> 3, js = tid & 7;          // staging row (0..31) / chunk (0..7)
  int gc = (js ^ (rs_ & 7)) * 8;             // swizzled global chunk (elements)
  int e = tid * 8;                           // linear LDS dest within 4KB segment
  int kq = lane >> 4;                        // read k-quarter within 32-K

  auto STAGE = [&](int buf, int k0) {
#pragma unroll
    for (int q = 0; q < 4; q++)
      gl_lds16(&A [(long)(m0 + q * 32 + rs_) * K + k0 + gc], &As[buf][q * 2048 + e]);
#pragma unroll
    for (int q = 0; q < 4; q++)
      gl_lds16(&WT[(long)(n0 + q * 32 + rs_) * K + k0 + gc], &Bs[buf][q * 2048 + e]);
  };

  int nIter = K >> 6;                        // K=512:8  K=768:12  K=2048:32
  STAGE(0, 0); STAGE(1, 64);                 // 16 loads in flight
  int cur = 0;
  int kc0 = (kq ^ (lrow & 7)) * 8;           // swizzled read chunk, s=0
  int kc1 = ((4 + kq) ^ (lrow & 7)) * 8;     // swizzled read chunk, s=1
  for (int it = 0; it < nIter; ++it) {
    if (it + 1 < nIter) VMCNT(8);            // wait only for buf[cur]'s 8 loads
    else               VMCNT(0);
    __builtin_amdgcn_s_barrier();            // buf[cur] visible to all waves
    bf16x8 af[2][4], bfr[2][4];
#pragma unroll
    for (int i = 0; i < 4; i++) {            // s=0 reads issued FIRST
      af[0][i]  = *reinterpret_cast<const bf16x8*>(&As[cur][(wm * 64 + i * 16 + lrow) * 64 + kc0]);
      bfr[0][i] = *reinterpret_cast<const bf16x8*>(&Bs[cur][(wn * 64 + i * 16 + lrow) * 64 + kc0]);
    }
    __builtin_amdgcn_sched_barrier(0);       // pin s=0 group before s=1
#pragma unroll
    for (int i = 0; i < 4; i++) {            // s=1 reads
      af[1][i]  = *reinterpret_cast<const bf16x8*>(&As[cur][(wm * 64 + i * 16 + lrow) * 64 + kc1]);
      bfr[1][i] = *reinterpret_cast<const bf16x8*>(&Bs[cur][(wn * 64 + i * 16 + lrow) * 64 + kc1]);
    }
    asm volatile("s_waitcnt lgkmcnt(8)");    // s=0's 8 reads done; s=1 in flight
    __builtin_amdgcn_sched_barrier(0);       // rule #18
    __builtin_amdgcn_s_setprio(1);
#pragma unroll
    for (int i = 0; i < 4; i++)              // s=0 MFMA overlaps s=1 ds_reads
#pragma unroll
      for (int j = 0; j < 4; j++)
        acc[i][j] = __builtin_amdgcn_mfma_f32_16x16x32_bf16(af[0][i], bfr[0][j], acc[i][j], 0, 0, 0);
    __builtin_amdgcn_s_setprio(0);
    asm volatile("s_waitcnt lgkmcnt(0)");    // all reads done -> safe to overwrite
    __builtin_amdgcn_sched_barrier(0);       // rule #18
    __builtin_amdgcn_s_barrier();            // all waves done reading buf[cur]
    if (it + 2 < nIter) STAGE(cur, (it + 2) << 6);   // overwrite with tile it+2
    __builtin_amdgcn_s_setprio(1);
#pragma unroll
    for (int i = 0; i < 4; i++)
#pragma unroll
      for (int j = 0; j < 4; j++)
        acc[i][j] = __builtin_amdgcn_mfma_f32_16x16x32_bf16(af[1][i], bfr[1][j], acc[i][j], 0, 0, 0);
    __builtin_amdgcn_s_setprio(0);
    cur ^= 1;
  }
  int rq = lane >> 4;
#pragma unroll
  for (int i = 0; i < 4; i++) {
#pragma unroll
    for (int j = 0; j < 4; j++) {
      int col = n0 + wn * 64 + j * 16 + lrow;
      float bv = bias[col];
#pragma unroll
      for (int rr = 0; rr < 4; rr++) {
        int rowg = m0 + wm * 64 + i * 16 + rq * 4 + rr;
        float v = acc[i][j][rr] + bv;
        if (POS) v += pos[(rowg & 15) * EDIM + col];
        if (RES) v += res[(long)rowg * N + col];
        if (RELU) v = fmaxf(v, 0.f);
        if (WF) outF[(long)rowg * N + col] = v;
        if (WB) outB[(long)rowg * N + col] = __float2bfloat16(v);
      }
    }
  }
}

// ======== spatial attention: 1 wave per (b*s, head); 16 patches, d=64 ========
__global__ __launch_bounds__(64) void k_attn_spatial(const bf16* __restrict__ qkv,
                                                     bf16* __restrict__ o) {
  __shared__ float qs[16][68], ks[16][68], vs[16][68], sc[16][17];
  int bs = blockIdx.x >> 3, h = blockIdx.x & 7;
  int lane = threadIdx.x;
  int R0 = bs * 16;
  int row = lane >> 2, d0 = (lane & 3) * 16;
  const bf16* bse = qkv + (long)(R0 + row) * 1536 + h * 64 + d0;
#pragma unroll
  for (int u = 0; u < 2; u++) {
    bf16x8 aq = *reinterpret_cast<const bf16x8*>(bse + u * 8);
    bf16x8 ak = *reinterpret_cast<const bf16x8*>(bse + 512 + u * 8);
    bf16x8 av = *reinterpret_cast<const bf16x8*>(bse + 1024 + u * 8);
#pragma unroll
    for (int e = 0; e < 8; e++) {
      qs[row][d0 + u * 8 + e] = bf2f(aq[e]);
      ks[row][d0 + u * 8 + e] = bf2f(ak[e]);
      vs[row][d0 + u * 8 + e] = bf2f(av[e]);
    }
  }
  __syncthreads();
  int i = lane >> 2, j0 = (lane & 3) * 4;
  for (int j = j0; j < j0 + 4; j++) {
    float d = 0.f;
    for (int kk = 0; kk < 64; kk++) d += qs[i][kk] * ks[j][kk];
    sc[i][j] = d * 0.125f;
  }
  __syncthreads();
  if (lane < 16) {
    float m = -1e30f;
    for (int j = 0; j < 16; j++) m = fmaxf(m, sc[lane][j]);
    float ssum = 0.f;
    for (int j = 0; j < 16; j++) { float e = __expf(sc[lane][j] - m); sc[lane][j] = e; ssum += e; }
    float inv = 1.f / ssum;
    for (int j = 0; j < 16; j++) sc[lane][j] *= inv;
  }
  __syncthreads();
  int dq = lane & 3;
  for (int dd = dq * 16; dd < dq * 16 + 16; dd++) {
    float acc = 0.f;
    for (int j = 0; j < 16; j++) acc += sc[i][j] * vs[j][dd];
    o[(long)(R0 + i) * EDIM + h * 64 + dd] = __float2bfloat16(acc);
  }
}

// ======== temporal causal attention, MFMA: 1 wave per (b, p, h); S=64, D=64 ====
__global__ __launch_bounds__(64) void k_attn_temporal_mfma(const bf16* __restrict__ qkv,
                                                           bf16* __restrict__ o) {
  __shared__ short Plds[64 * 72];   // P[s_q][s_k], row stride 72 bf16 (144B)
  __shared__ short VT[64 * 72];     // VT[d][s ^ ((d>>3&7)<<3)], row stride 72
  int bp = blockIdx.x >> 3, h = blockIdx.x & 7;
  int b = bp >> 4, p = bp & 15;
  int lane = threadIdx.x;
  int c = lane & 15, q = lane >> 4;
  const long RSTR = 16 * 1536;      // row (time-step) stride in qkv elements
  const bf16* qb = qkv + ((long)(b * 1024 + p)) * 1536 + h * 64;

  {
    bf16x8 z = {};
#pragma unroll
    for (int t = 0; t < 9; t++)
      *reinterpret_cast<bf16x8*>(&Plds[(t * 64 + lane) * 8]) = z;
  }
#pragma unroll
  for (int t = 0; t < 8; t++) {
    int s = t * 8 + (lane >> 3), d0 = (lane & 7) * 8;
    bf16x8 v = *reinterpret_cast<const bf16x8*>(qb + 1024 + (long)s * RSTR + d0);
#pragma unroll
    for (int u = 0; u < 8; u++) {
      int d = d0 + u;
      VT[d * 72 + (s ^ (((d >> 3) & 7) << 3))] = v[u];
    }
  }
  __syncthreads();

  f32x4 sAcc[4][4] = {};
#pragma unroll
  for (int ks = 0; ks < 2; ks++) {
    bf16x8 kf[4];
#pragma unroll
    for (int j = 0; j < 4; j++)
      kf[j] = *reinterpret_cast<const bf16x8*>(qb + 512 + (long)(16 * j + c) * RSTR + 32 * ks + 8 * q);
#pragma unroll
    for (int i = 0; i < 4; i++) {
      bf16x8 qf = *reinterpret_cast<const bf16x8*>(qb + (long)(16 * i + c) * RSTR + 32 * ks + 8 * q);
#pragma unroll
      for (int j = 0; j < 4; j++)
        if (j <= i)
          sAcc[i][j] = __builtin_amdgcn_mfma_f32_16x16x32_bf16(qf, kf[j], sAcc[i][j], 0, 0, 0);
    }
  }

  f32x4 invs[4];
#pragma unroll
  for (int i = 0; i < 4; i++) {
    f32x4 mx;
#pragma unroll
    for (int r = 0; r < 4; r++) mx[r] = -1e30f;
#pragma unroll
    for (int j = 0; j <= i; j++)
#pragma unroll
      for (int r = 0; r < 4; r++) {
        float v = sAcc[i][j][r] * 0.125f;
        if (j == i && c > 4 * q + r) v = -1e30f;
        sAcc[i][j][r] = v;
        mx[r] = fmaxf(mx[r], v);
      }
#pragma unroll
    for (int off = 1; off < 16; off <<= 1)
#pragma unroll
      for (int r = 0; r < 4; r++) mx[r] = fmaxf(mx[r], __shfl_xor(mx[r], off));
    f32x4 sm = {};
#pragma unroll
    for (int j = 0; j <= i; j++)
#pragma unroll
      for (int r = 0; r < 4; r++) {
        float e = __expf(sAcc[i][j][r] - mx[r]);
        sm[r] += e;
        Plds[(16 * i + 4 * q + r) * 72 + 16 * j + c] = f2bf(e);
      }
#pragma unroll
    for (int off = 1; off < 16; off <<= 1)
#pragma unroll
      for (int r = 0; r < 4; r++) sm[r] += __shfl_xor(sm[r], off);
#pragma unroll
    for (int r = 0; r < 4; r++) invs[i][r] = 1.f / sm[r];
  }
  __syncthreads();

  f32x4 oacc[4][4] = {};
#pragma unroll
  for (int kb = 0; kb < 2; kb++) {
    bf16x8 vb[4];
#pragma unroll
    for (int db = 0; db < 4; db++) {
      int d = 16 * db + c;
      vb[db] = *reinterpret_cast<const bf16x8*>(&VT[d * 72 + ((32 * kb + 8 * q) ^ (((d >> 3) & 7) << 3))]);
    }
#pragma unroll
    for (int i = 0; i < 4; i++) {
      if (kb == 1 && i < 2) continue;
      bf16x8 pa = *reinterpret_cast<const bf16x8*>(&Plds[(16 * i + c) * 72 + 32 * kb + 8 * q]);
#pragma unroll
      for (int db = 0; db < 4; db++)
        oacc[i][db] = __builtin_amdgcn_mfma_f32_16x16x32_bf16(pa, vb[db], oacc[i][db], 0, 0, 0);
    }
  }

#pragma unroll
  for (int i = 0; i < 4; i++)
#pragma unroll
    for (int db = 0; db < 4; db++)
#pragma unroll
      for (int r = 0; r < 4; r++) {
        int srow = 16 * i + 4 * q + r;
        long tok = (long)(b * 64 + srow) * 16 + p;
        o[tok * EDIM + h * 64 + 16 * db + c] = __float2bfloat16(oacc[i][db][r] * invs[i][r]);
      }
}

// ======== LayerNorm over 512: 4 rows per 256-thr block (wave per row) ========
__global__ __launch_bounds__(256) void k_ln(const float* __restrict__ r,
                                            const float* __restrict__ g,
                                            const float* __restrict__ b,
                                            float* __restrict__ xf,
                                            bf16* __restrict__ xb) {
  int row = blockIdx.x * 4 + (threadIdx.x >> 6);
  int lane = threadIdx.x & 63;
  const float4* rp = reinterpret_cast<const float4*>(r + (long)row * EDIM);
  float4 a = rp[lane * 2], c = rp[lane * 2 + 1];
  float s = a.x + a.y + a.z + a.w + c.x + c.y + c.z + c.w;
  float q = a.x * a.x + a.y * a.y + a.z * a.z + a.w * a.w +
            c.x * c.x + c.y * c.y + c.z * c.z + c.w * c.w;
#pragma unroll
  for (int off = 32; off; off >>= 1) { s += __shfl_xor(s, off); q += __shfl_xor(q, off); }
  float mean = s * (1.f / EDIM);
  float var = q * (1.f / EDIM) - mean * mean;
  float rs = rsqrtf(var + 1e-5f);
  float vals[8] = {a.x, a.y, a.z, a.w, c.x, c.y, c.z, c.w};
  long base = (long)row * EDIM + lane * 8;
#pragma unroll
  for (int u = 0; u < 8; u++) {
    int cidx = lane * 8 + u;
    float y = (vals[u] - mean) * rs * g[cidx] + b[cidx];
    xf[base + u] = y;
    xb[base + u] = __float2bfloat16(y);
  }
}

// ======== head: pool over patches, pair-concat, LN(1024), @ h_w + h_b ========
__global__ __launch_bounds__(256) void k_head(const float* __restrict__ xf,
                                              const float* __restrict__ g,
                                              const float* __restrict__ b,
                                              const float* __restrict__ hw,
                                              const float* __restrict__ hb,
                                              float* __restrict__ actions) {
  __shared__ float lnv[1024];
  __shared__ float red[10];
  int blk = blockIdx.x;               // 16*63
  int bb = blk / 63, t = blk % 63;
  int tid = threadIdx.x;
  float vals[4];
  float s = 0.f, q = 0.f;
#pragma unroll
  for (int u = 0; u < 4; u++) {
    int idx = tid * 4 + u;            // 0..1023
    int half = idx >> 9, e = idx & 511;
    const float* base = xf + (long)(((bb * 64) + t + half) * 16) * EDIM + e;
    float acc = 0.f;
#pragma unroll
    for (int p = 0; p < 16; p++) acc += base[p * EDIM];
    acc *= (1.f / 16.f);
    vals[u] = acc; s += acc; q += acc * acc;
  }
#pragma unroll
  for (int off = 32; off; off >>= 1) { s += __shfl_xor(s, off); q += __shfl_xor(q, off); }
  if ((tid & 63) == 0) { red[tid >> 6] = s; red[4 + (tid >> 6)] = q; }
  __syncthreads();
  if (tid == 0) {
    float S = red[0] + red[1] + red[2] + red[3];
    float Q = red[4] + red[5] + red[6] + red[7];
    float m = S * (1.f / 1024.f);
    red[8] = m;
    red[9] = rsqrtf(Q * (1.f / 1024.f) - m * m + 1e-5f);
  }
  __syncthreads();
  float m = red[8], rs = red[9];
#pragma unroll
  for (int u = 0; u < 4; u++) {
    int idx = tid * 4 + u;
    lnv[idx] = (vals[u] - m) * rs * g[idx] + b[idx];
  }
  __syncthreads();
  if (tid < 64) {
    float acc = hb[tid];
    for (int e = 0; e < 1024; e++) acc += lnv[e] * hw[e * 64 + tid];
    actions[(long)blk * 64 + tid] = acc;
  }
}

extern "C" void kernel_launch(void* const* d_in, const int* in_sizes, int n_in,
                              void* d_out, int out_size, void* d_ws, size_t ws_size,
                              hipStream_t stream) {
  (void)in_sizes; (void)n_in; (void)out_size; (void)ws_size;
  const float* frames  = (const float*)d_in[0];
  const float* w_patch = (const float*)d_in[1];
  const float* b_patch = (const float*)d_in[2];
  const float* pos     = (const float*)d_in[3];
  const float* s_w[4]  = {(const float*)d_in[4],  (const float*)d_in[5],
                          (const float*)d_in[6],  (const float*)d_in[7]};
  const float* s_bq = (const float*)d_in[8];
  const float* s_bk = (const float*)d_in[9];
  const float* s_bv = (const float*)d_in[10];
  const float* s_bo = (const float*)d_in[11];
  const float* s_lng = (const float*)d_in[12];
  const float* s_lnb = (const float*)d_in[13];
  const float* t_w[4]  = {(const float*)d_in[14], (const float*)d_in[15],
                          (const float*)d_in[16], (const float*)d_in[17]};
  const float* t_bq = (const float*)d_in[18];
  const float* t_bk = (const float*)d_in[19];
  const float* t_bv = (const float*)d_in[20];
  const float* t_bo = (const float*)d_in[21];
  const float* t_lng = (const float*)d_in[22];
  const float* t_lnb = (const float*)d_in[23];
  const float* f_w1 = (const float*)d_in[24];
  const float* f_b1 = (const float*)d_in[25];
  const float* f_w2 = (const float*)d_in[26];
  const float* f_b2 = (const float*)d_in[27];
  const float* f_lng = (const float*)d_in[28];
  const float* f_lnb = (const float*)d_in[29];
  const float* h_lng = (const float*)d_in[30];
  const float* h_lnb = (const float*)d_in[31];
  const float* h_w = (const float*)d_in[32];
  const float* h_b = (const float*)d_in[33];

  char* ws = (char*)d_ws;
  size_t off = 0;
  auto alloc = [&](size_t bytes) { size_t o = off; off += (bytes + 255) & ~(size_t)255; return o; };
  bf16* sqkvT = (bf16*)(ws + alloc((size_t)6 * 1536 * 512 * 2));
  bf16* swoT  = (bf16*)(ws + alloc((size_t)6 * 512 * 512 * 2));
  bf16* tqkvT = (bf16*)(ws + alloc((size_t)6 * 1536 * 512 * 2));
  bf16* twoT  = (bf16*)(ws + alloc((size_t)6 * 512 * 512 * 2));
  bf16* w1T   = (bf16*)(ws + alloc((size_t)6 * 2048 * 512 * 2));
  bf16* w2T   = (bf16*)(ws + alloc((size_t)6 * 512 * 2048 * 2));
  bf16* wpT   = (bf16*)(ws + alloc((size_t)512 * 768 * 2));
  float* bqkv = (float*)(ws + alloc((size_t)2 * 6 * 1536 * 4));
  float* xf   = (float*)(ws + alloc((size_t)NTOK * EDIM * 4));
  bf16* xb    = (bf16*)(ws + alloc((size_t)NTOK * EDIM * 2));
  char* regC  = ws + alloc((size_t)NTOK * 1536 * 2);   // qkv bf16 | r fp32 (phase-disjoint)
  char* regD  = ws + alloc((size_t)NTOK * 2048 * 2);   // P | o | h1 (phase-disjoint)
  bf16* qkv  = (bf16*)regC;
  float* rbuf = (float*)regC;
  bf16* Pmat = (bf16*)regD;
  bf16* obuf = (bf16*)regD;
  bf16* h1   = (bf16*)regD;

  dim3 tb(32, 8);
  for (int pre = 0; pre < 2; pre++) {
    const float* const* wsrc = pre ? t_w : s_w;
    bf16* qdst = pre ? tqkvT : sqkvT;
    bf16* odst = pre ? twoT : swoT;
    for (int wi = 0; wi < 3; wi++)
      k_transpose<<<dim3(16, 16, 6), tb, 0, stream>>>(wsrc[wi], qdst + wi * 512 * 512,
                                                      512, 512, 262144L, 786432L);
    k_transpose<<<dim3(16, 16, 6), tb, 0, stream>>>(wsrc[3], odst, 512, 512, 262144L, 262144L);
  }
  k_transpose<<<dim3(64, 16, 6), tb, 0, stream>>>(f_w1, w1T, 512, 2048, 1048576L, 1048576L);
  k_transpose<<<dim3(16, 64, 6), tb, 0, stream>>>(f_w2, w2T, 2048, 512, 1048576L, 1048576L);
  k_transpose<<<dim3(16, 24, 1), tb, 0, stream>>>(w_patch, wpT, 768, 512, 0L, 0L);
  k_pack_bias<<<72, 256, 0, stream>>>(s_bq, s_bk, s_bv, t_bq, t_bk, t_bv, bqkv);

  k_patchify<<<6144, 256, 0, stream>>>(frames, Pmat);
  // grids: all 1D, count % 8 == 0 (bijective XCD swizzle requirement)
  k_gemm<0, 0, 1, 1, 1><<<512, 256, 0, stream>>>(
      Pmat, wpT, b_patch, nullptr, pos, xf, xb, 512, 768, 4);

  float* out = (float*)d_out;
  float* xf_final = out + 64512;   // second output: x fp32, written by last LN

  for (int l = 0; l < 6; l++) {
    // ---- spatial attention ----
    k_gemm<0, 0, 0, 0, 1><<<1536, 256, 0, stream>>>(
        xb, sqkvT + (size_t)l * 1536 * 512, bqkv + l * 1536,
        nullptr, nullptr, nullptr, qkv, 1536, 512, 12);
    k_attn_spatial<<<8192, 64, 0, stream>>>(qkv, obuf);
    k_gemm<0, 1, 0, 1, 0><<<512, 256, 0, stream>>>(
        obuf, swoT + (size_t)l * 512 * 512, s_bo + l * 512,
        xf, nullptr, rbuf, nullptr, 512, 512, 4);
    k_ln<<<NTOK / 4, 256, 0, stream>>>(rbuf, s_lng + l * 512, s_lnb + l * 512, xf, xb);
    // ---- temporal attention ----
    k_gemm<0, 0, 0, 0, 1><<<1536, 256, 0, stream>>>(
        xb, tqkvT + (size_t)l * 1536 * 512, bqkv + (6 + l) * 1536,
        nullptr, nullptr, nullptr, qkv, 1536, 512, 12);
    k_attn_temporal_mfma<<<2048, 64, 0, stream>>>(qkv, obuf);
    k_gemm<0, 1, 0, 1, 0><<<512, 256, 0, stream>>>(
        obuf, twoT + (size_t)l * 512 * 512, t_bo + l * 512,
        xf, nullptr, rbuf, nullptr, 512, 512, 4);
    k_ln<<<NTOK / 4, 256, 0, stream>>>(rbuf, t_lng + l * 512, t_lnb + l * 512, xf, xb);
    // ---- FFN ----
    k_gemm<1, 0, 0, 0, 1><<<2048, 256, 0, stream>>>(
        xb, w1T + (size_t)l * 2048 * 512, f_b1 + l * 2048,
        nullptr, nullptr, nullptr, h1, 2048, 512, 16);
    k_gemm<0, 1, 0, 1, 0><<<512, 256, 0, stream>>>(
        h1, w2T + (size_t)l * 512 * 2048, f_b2 + l * 512,
        xf, nullptr, rbuf, nullptr, 512, 2048, 4);
    float* xf_out = (l == 5) ? xf_final : xf;
    k_ln<<<NTOK / 4, 256, 0, stream>>>(rbuf, f_lng + l * 512, f_lnb + l * 512, xf_out, xb);
  }

  k_head<<<1008, 256, 0, stream>>>(xf_final, h_lng, h_lnb, h_w, h_b, out);
}

// Round 11
// 1935.142 us; speedup vs baseline: 1.1130x; 1.0158x over previous
//
#include <hip/hip_runtime.h>
#include <hip/hip_bf16.h>

typedef _Float16 f16;
typedef _Float16 f16x8 __attribute__((ext_vector_type(8)));
typedef float f32x4 __attribute__((ext_vector_type(4)));

#define NTOK 16384   // 16*64*16 tokens
#define EDIM 512
#define FFDIM 2048
#define PDIM 768

#define VMCNT(n) asm volatile("s_waitcnt vmcnt(" #n ")")

// async global->LDS DMA, 16B per lane. LDS dest must be linear in lane order.
typedef __attribute__((address_space(3))) unsigned int lds_uint;
typedef __attribute__((address_space(1))) const unsigned int glob_uint;
__device__ __forceinline__ void gl_lds16(const f16* g, f16* l) {
  __builtin_amdgcn_global_load_lds((glob_uint*)g, (lds_uint*)l, 16, 0, 0);
}

// ======== weight transpose: fp32 [B][R][C] -> fp16 [B][C][R] ========
__global__ void k_transpose(const float* __restrict__ src, f16* __restrict__ dst,
                            int R, int C, long srcBS, long dstBS) {
  __shared__ float tile[32][33];
  src += (long)blockIdx.z * srcBS;
  dst += (long)blockIdx.z * dstBS;
  int c0 = blockIdx.x * 32, r0 = blockIdx.y * 32;
  int tx = threadIdx.x, ty = threadIdx.y;
#pragma unroll
  for (int j = ty; j < 32; j += 8)
    tile[j][tx] = src[(long)(r0 + j) * C + (c0 + tx)];
  __syncthreads();
#pragma unroll
  for (int j = ty; j < 32; j += 8)
    dst[(long)(c0 + j) * R + (r0 + tx)] = (f16)tile[tx][j];
}

// ======== pack QKV biases -> [2][6][1536] fp32 ========
__global__ void k_pack_bias(const float* __restrict__ sq, const float* __restrict__ sk,
                            const float* __restrict__ sv, const float* __restrict__ tq,
                            const float* __restrict__ tk, const float* __restrict__ tv,
                            float* __restrict__ dst) {
  int i = blockIdx.x * 256 + threadIdx.x;
  if (i >= 2 * 6 * 1536) return;
  int pre = i / (6 * 1536), rem = i % (6 * 1536), l = rem / 1536, e = rem % 1536;
  const float* s;
  if (pre == 0) s = (e < 512) ? sq : (e < 1024) ? sk : sv;
  else          s = (e < 512) ? tq : (e < 1024) ? tk : tv;
  dst[i] = s[l * 512 + (e & 511)];
}

// ======== patchify: frames fp32 [16][64][3][64][64] -> P fp16 [16384][768] ========
__global__ void k_patchify(const float* __restrict__ frames, f16* __restrict__ P) {
  int gid = blockIdx.x * 256 + threadIdx.x;           // < 16384*96
  int token = gid / 96, chunk = gid % 96;
  int b = token >> 10, s = (token >> 4) & 63, p = token & 15;
  int c = chunk >> 5, rem = chunk & 31, p1 = rem >> 1, p2b = (rem & 1) * 8;
  int h = p >> 2, w = p & 3;
  const float* src = frames + ((long)(((b * 64 + s) * 3 + c) * 64 + h * 16 + p1)) * 64 + w * 16 + p2b;
  float4 f0 = *reinterpret_cast<const float4*>(src);
  float4 f1 = *reinterpret_cast<const float4*>(src + 4);
  f16* dst = P + (long)token * PDIM + chunk * 8;
  dst[0] = (f16)f0.x; dst[1] = (f16)f0.y; dst[2] = (f16)f0.z; dst[3] = (f16)f0.w;
  dst[4] = (f16)f1.x; dst[5] = (f16)f1.y; dst[6] = (f16)f1.z; dst[7] = (f16)f1.w;
}

// ======== MFMA GEMM, BK=64 2-deep counted-vmcnt pipeline (R9 structure) ======
// 128x128 tile, BK=64, 4 waves (2x2). Double-buffered global_load_lds staging,
// counted vmcnt(8) across barriers, split lgkmcnt(8), both-sides chunk-XOR
// swizzle, XCD-bijective 1D grid. fp16 datapath; fp32 accumulate/epilogue.
template <int RELU, int RESH, int POS>
__global__ __launch_bounds__(256, 2) void k_gemm(
    const f16* __restrict__ A, const f16* __restrict__ WT,
    const float* __restrict__ bias, const f16* __restrict__ resH,
    const float* __restrict__ pos, f16* __restrict__ outH,
    int N, int K, int nwgx) {
  __shared__ f16 As[2][128 * 64];
  __shared__ f16 Bs[2][128 * 64];
  int tid = threadIdx.x;
  int wave = tid >> 6, lane = tid & 63;
  int wm = wave >> 1, wn = wave & 1;
  int nwg = gridDim.x;
  int id = blockIdx.x;
  int sw = (id & 7) * (nwg >> 3) + (id >> 3);
  int m0 = (sw / nwgx) * 128, n0 = (sw % nwgx) * 128;
  f32x4 acc[4][4] = {};
  int lrow = lane & 15;
  int rs_ = tid >> 3, js = tid & 7;
  int gc = (js ^ (rs_ & 7)) * 8;
  int e = tid * 8;
  int kq = lane >> 4;

  auto STAGE = [&](int buf, int k0) {
#pragma unroll
    for (int q = 0; q < 4; q++)
      gl_lds16(&A [(long)(m0 + q * 32 + rs_) * K + k0 + gc], &As[buf][q * 2048 + e]);
#pragma unroll
    for (int q = 0; q < 4; q++)
      gl_lds16(&WT[(long)(n0 + q * 32 + rs_) * K + k0 + gc], &Bs[buf][q * 2048 + e]);
  };

  int nIter = K >> 6;
  STAGE(0, 0); STAGE(1, 64);
  int cur = 0;
  int kc0 = (kq ^ (lrow & 7)) * 8;
  int kc1 = ((4 + kq) ^ (lrow & 7)) * 8;
  for (int it = 0; it < nIter; ++it) {
    if (it + 1 < nIter) VMCNT(8);
    else               VMCNT(0);
    __builtin_amdgcn_s_barrier();
    f16x8 af[2][4], bfr[2][4];
#pragma unroll
    for (int i = 0; i < 4; i++) {
      af[0][i]  = *reinterpret_cast<const f16x8*>(&As[cur][(wm * 64 + i * 16 + lrow) * 64 + kc0]);
      bfr[0][i] = *reinterpret_cast<const f16x8*>(&Bs[cur][(wn * 64 + i * 16 + lrow) * 64 + kc0]);
    }
    __builtin_amdgcn_sched_barrier(0);
#pragma unroll
    for (int i = 0; i < 4; i++) {
      af[1][i]  = *reinterpret_cast<const f16x8*>(&As[cur][(wm * 64 + i * 16 + lrow) * 64 + kc1]);
      bfr[1][i] = *reinterpret_cast<const f16x8*>(&Bs[cur][(wn * 64 + i * 16 + lrow) * 64 + kc1]);
    }
    asm volatile("s_waitcnt lgkmcnt(8)");
    __builtin_amdgcn_sched_barrier(0);
    __builtin_amdgcn_s_setprio(1);
#pragma unroll
    for (int i = 0; i < 4; i++)
#pragma unroll
      for (int j = 0; j < 4; j++)
        acc[i][j] = __builtin_amdgcn_mfma_f32_16x16x32_f16(af[0][i], bfr[0][j], acc[i][j], 0, 0, 0);
    __builtin_amdgcn_s_setprio(0);
    asm volatile("s_waitcnt lgkmcnt(0)");
    __builtin_amdgcn_sched_barrier(0);
    __builtin_amdgcn_s_barrier();
    if (it + 2 < nIter) STAGE(cur, (it + 2) << 6);
    __builtin_amdgcn_s_setprio(1);
#pragma unroll
    for (int i = 0; i < 4; i++)
#pragma unroll
      for (int j = 0; j < 4; j++)
        acc[i][j] = __builtin_amdgcn_mfma_f32_16x16x32_f16(af[1][i], bfr[1][j], acc[i][j], 0, 0, 0);
    __builtin_amdgcn_s_setprio(0);
    cur ^= 1;
  }
  int rq = lane >> 4;
#pragma unroll
  for (int i = 0; i < 4; i++) {
#pragma unroll
    for (int j = 0; j < 4; j++) {
      int col = n0 + wn * 64 + j * 16 + lrow;
      float bv = bias[col];
#pragma unroll
      for (int rr = 0; rr < 4; rr++) {
        int rowg = m0 + wm * 64 + i * 16 + rq * 4 + rr;
        float v = acc[i][j][rr] + bv;
        if (POS) v += pos[(rowg & 15) * EDIM + col];
        if (RESH) v += (float)resH[(long)rowg * N + col];
        if (RELU) v = fmaxf(v, 0.f);
        outH[(long)rowg * N + col] = (f16)v;
      }
    }
  }
}

// ======== spatial attention: 1 wave per (b*s, head); 16 patches, d=64 ========
__global__ __launch_bounds__(64) void k_attn_spatial(const f16* __restrict__ qkv,
                                                     f16* __restrict__ o) {
  __shared__ float qs[16][68], ks[16][68], vs[16][68], sc[16][17];
  int bs = blockIdx.x >> 3, h = blockIdx.x & 7;
  int lane = threadIdx.x;
  int R0 = bs * 16;
  int row = lane >> 2, d0 = (lane & 3) * 16;
  const f16* bse = qkv + (long)(R0 + row) * 1536 + h * 64 + d0;
#pragma unroll
  for (int u = 0; u < 2; u++) {
    f16x8 aq = *reinterpret_cast<const f16x8*>(bse + u * 8);
    f16x8 ak = *reinterpret_cast<const f16x8*>(bse + 512 + u * 8);
    f16x8 av = *reinterpret_cast<const f16x8*>(bse + 1024 + u * 8);
#pragma unroll
    for (int e = 0; e < 8; e++) {
      qs[row][d0 + u * 8 + e] = (float)aq[e];
      ks[row][d0 + u * 8 + e] = (float)ak[e];
      vs[row][d0 + u * 8 + e] = (float)av[e];
    }
  }
  __syncthreads();
  int i = lane >> 2, j0 = (lane & 3) * 4;
  for (int j = j0; j < j0 + 4; j++) {
    float d = 0.f;
    for (int kk = 0; kk < 64; kk++) d += qs[i][kk] * ks[j][kk];
    sc[i][j] = d * 0.125f;
  }
  __syncthreads();
  if (lane < 16) {
    float m = -1e30f;
    for (int j = 0; j < 16; j++) m = fmaxf(m, sc[lane][j]);
    float ssum = 0.f;
    for (int j = 0; j < 16; j++) { float e = __expf(sc[lane][j] - m); sc[lane][j] = e; ssum += e; }
    float inv = 1.f / ssum;
    for (int j = 0; j < 16; j++) sc[lane][j] *= inv;
  }
  __syncthreads();
  int dq = lane & 3;
  for (int dd = dq * 16; dd < dq * 16 + 16; dd++) {
    float acc = 0.f;
    for (int j = 0; j < 16; j++) acc += sc[i][j] * vs[j][dd];
    o[(long)(R0 + i) * EDIM + h * 64 + dd] = (f16)acc;
  }
}

// ======== temporal causal attention, MFMA: 1 wave per (b, p, h); S=64, D=64 ====
__global__ __launch_bounds__(64) void k_attn_temporal_mfma(const f16* __restrict__ qkv,
                                                           f16* __restrict__ o) {
  __shared__ f16 Plds[64 * 72];   // P[s_q][s_k], row stride 72 f16 (144B)
  __shared__ f16 VT[64 * 72];     // VT[d][s ^ ((d>>3&7)<<3)], row stride 72
  int bp = blockIdx.x >> 3, h = blockIdx.x & 7;
  int b = bp >> 4, p = bp & 15;
  int lane = threadIdx.x;
  int c = lane & 15, q = lane >> 4;
  const long RSTR = 16 * 1536;
  const f16* qb = qkv + ((long)(b * 1024 + p)) * 1536 + h * 64;

  {
    f16x8 z = {};
#pragma unroll
    for (int t = 0; t < 9; t++)
      *reinterpret_cast<f16x8*>(&Plds[(t * 64 + lane) * 8]) = z;
  }
#pragma unroll
  for (int t = 0; t < 8; t++) {
    int s = t * 8 + (lane >> 3), d0 = (lane & 7) * 8;
    f16x8 v = *reinterpret_cast<const f16x8*>(qb + 1024 + (long)s * RSTR + d0);
#pragma unroll
    for (int u = 0; u < 8; u++) {
      int d = d0 + u;
      VT[d * 72 + (s ^ (((d >> 3) & 7) << 3))] = v[u];
    }
  }
  __syncthreads();

  f32x4 sAcc[4][4] = {};
#pragma unroll
  for (int ks = 0; ks < 2; ks++) {
    f16x8 kf[4];
#pragma unroll
    for (int j = 0; j < 4; j++)
      kf[j] = *reinterpret_cast<const f16x8*>(qb + 512 + (long)(16 * j + c) * RSTR + 32 * ks + 8 * q);
#pragma unroll
    for (int i = 0; i < 4; i++) {
      f16x8 qf = *reinterpret_cast<const f16x8*>(qb + (long)(16 * i + c) * RSTR + 32 * ks + 8 * q);
#pragma unroll
      for (int j = 0; j < 4; j++)
        if (j <= i)
          sAcc[i][j] = __builtin_amdgcn_mfma_f32_16x16x32_f16(qf, kf[j], sAcc[i][j], 0, 0, 0);
    }
  }

  f32x4 invs[4];
#pragma unroll
  for (int i = 0; i < 4; i++) {
    f32x4 mx;
#pragma unroll
    for (int r = 0; r < 4; r++) mx[r] = -1e30f;
#pragma unroll
    for (int j = 0; j <= i; j++)
#pragma unroll
      for (int r = 0; r < 4; r++) {
        float v = sAcc[i][j][r] * 0.125f;
        if (j == i && c > 4 * q + r) v = -1e30f;
        sAcc[i][j][r] = v;
        mx[r] = fmaxf(mx[r], v);
      }
#pragma unroll
    for (int off = 1; off < 16; off <<= 1)
#pragma unroll
      for (int r = 0; r < 4; r++) mx[r] = fmaxf(mx[r], __shfl_xor(mx[r], off));
    f32x4 sm = {};
#pragma unroll
    for (int j = 0; j <= i; j++)
#pragma unroll
      for (int r = 0; r < 4; r++) {
        float e = __expf(sAcc[i][j][r] - mx[r]);
        sm[r] += e;
        Plds[(16 * i + 4 * q + r) * 72 + 16 * j + c] = (f16)e;
      }
#pragma unroll
    for (int off = 1; off < 16; off <<= 1)
#pragma unroll
      for (int r = 0; r < 4; r++) sm[r] += __shfl_xor(sm[r], off);
#pragma unroll
    for (int r = 0; r < 4; r++) invs[i][r] = 1.f / sm[r];
  }
  __syncthreads();

  f32x4 oacc[4][4] = {};
#pragma unroll
  for (int kb = 0; kb < 2; kb++) {
    f16x8 vb[4];
#pragma unroll
    for (int db = 0; db < 4; db++) {
      int d = 16 * db + c;
      vb[db] = *reinterpret_cast<const f16x8*>(&VT[d * 72 + ((32 * kb + 8 * q) ^ (((d >> 3) & 7) << 3))]);
    }
#pragma unroll
    for (int i = 0; i < 4; i++) {
      if (kb == 1 && i < 2) continue;
      f16x8 pa = *reinterpret_cast<const f16x8*>(&Plds[(16 * i + c) * 72 + 32 * kb + 8 * q]);
#pragma unroll
      for (int db = 0; db < 4; db++)
        oacc[i][db] = __builtin_amdgcn_mfma_f32_16x16x32_f16(pa, vb[db], oacc[i][db], 0, 0, 0);
    }
  }

#pragma unroll
  for (int i = 0; i < 4; i++)
#pragma unroll
    for (int db = 0; db < 4; db++)
#pragma unroll
      for (int r = 0; r < 4; r++) {
        int srow = 16 * i + 4 * q + r;
        long tok = (long)(b * 64 + srow) * 16 + p;
        o[tok * EDIM + h * 64 + 16 * db + c] = (f16)(oacc[i][db][r] * invs[i][r]);
      }
}

// ======== LayerNorm over 512 (fp16 in): 4 rows per 256-thr block ========
// FINAL=0: write xh (fp16). FINAL=1: write xf (fp32).
template <int FINAL>
__global__ __launch_bounds__(256) void k_ln_h(const f16* __restrict__ r,
                                              const float* __restrict__ g,
                                              const float* __restrict__ b,
                                              float* __restrict__ xf,
                                              f16* __restrict__ xh) {
  int row = blockIdx.x * 4 + (threadIdx.x >> 6);
  int lane = threadIdx.x & 63;
  f16x8 v = *reinterpret_cast<const f16x8*>(r + (long)row * EDIM + lane * 8);
  float vals[8];
  float s = 0.f, q = 0.f;
#pragma unroll
  for (int u = 0; u < 8; u++) {
    vals[u] = (float)v[u];
    s += vals[u]; q += vals[u] * vals[u];
  }
#pragma unroll
  for (int off = 32; off; off >>= 1) { s += __shfl_xor(s, off); q += __shfl_xor(q, off); }
  float mean = s * (1.f / EDIM);
  float var = q * (1.f / EDIM) - mean * mean;
  float rs = rsqrtf(var + 1e-5f);
  long base = (long)row * EDIM + lane * 8;
  if (FINAL) {
#pragma unroll
    for (int u = 0; u < 8; u++) {
      int cidx = lane * 8 + u;
      xf[base + u] = (vals[u] - mean) * rs * g[cidx] + b[cidx];
    }
  } else {
    f16x8 y;
#pragma unroll
    for (int u = 0; u < 8; u++) {
      int cidx = lane * 8 + u;
      y[u] = (f16)((vals[u] - mean) * rs * g[cidx] + b[cidx]);
    }
    *reinterpret_cast<f16x8*>(xh + base) = y;
  }
}

// ======== head: pool over patches, pair-concat, LN(1024), @ h_w + h_b ========
__global__ __launch_bounds__(256) void k_head(const float* __restrict__ xf,
                                              const float* __restrict__ g,
                                              const float* __restrict__ b,
                                              const float* __restrict__ hw,
                                              const float* __restrict__ hb,
                                              float* __restrict__ actions) {
  __shared__ float lnv[1024];
  __shared__ float red[10];
  int blk = blockIdx.x;               // 16*63
  int bb = blk / 63, t = blk % 63;
  int tid = threadIdx.x;
  float vals[4];
  float s = 0.f, q = 0.f;
#pragma unroll
  for (int u = 0; u < 4; u++) {
    int idx = tid * 4 + u;            // 0..1023
    int half = idx >> 9, e = idx & 511;
    const float* base = xf + (long)(((bb * 64) + t + half) * 16) * EDIM + e;
    float acc = 0.f;
#pragma unroll
    for (int p = 0; p < 16; p++) acc += base[p * EDIM];
    acc *= (1.f / 16.f);
    vals[u] = acc; s += acc; q += acc * acc;
  }
#pragma unroll
  for (int off = 32; off; off >>= 1) { s += __shfl_xor(s, off); q += __shfl_xor(q, off); }
  if ((tid & 63) == 0) { red[tid >> 6] = s; red[4 + (tid >> 6)] = q; }
  __syncthreads();
  if (tid == 0) {
    float S = red[0] + red[1] + red[2] + red[3];
    float Q = red[4] + red[5] + red[6] + red[7];
    float m = S * (1.f / 1024.f);
    red[8] = m;
    red[9] = rsqrtf(Q * (1.f / 1024.f) - m * m + 1e-5f);
  }
  __syncthreads();
  float m = red[8], rs = red[9];
#pragma unroll
  for (int u = 0; u < 4; u++) {
    int idx = tid * 4 + u;
    lnv[idx] = (vals[u] - m) * rs * g[idx] + b[idx];
  }
  __syncthreads();
  if (tid < 64) {
    float acc = hb[tid];
    for (int e = 0; e < 1024; e++) acc += lnv[e] * hw[e * 64 + tid];
    actions[(long)blk * 64 + tid] = acc;
  }
}

extern "C" void kernel_launch(void* const* d_in, const int* in_sizes, int n_in,
                              void* d_out, int out_size, void* d_ws, size_t ws_size,
                              hipStream_t stream) {
  (void)in_sizes; (void)n_in; (void)out_size; (void)ws_size;
  const float* frames  = (const float*)d_in[0];
  const float* w_patch = (const float*)d_in[1];
  const float* b_patch = (const float*)d_in[2];
  const float* pos     = (const float*)d_in[3];
  const float* s_w[4]  = {(const float*)d_in[4],  (const float*)d_in[5],
                          (const float*)d_in[6],  (const float*)d_in[7]};
  const float* s_bq = (const float*)d_in[8];
  const float* s_bk = (const float*)d_in[9];
  const float* s_bv = (const float*)d_in[10];
  const float* s_bo = (const float*)d_in[11];
  const float* s_lng = (const float*)d_in[12];
  const float* s_lnb = (const float*)d_in[13];
  const float* t_w[4]  = {(const float*)d_in[14], (const float*)d_in[15],
                          (const float*)d_in[16], (const float*)d_in[17]};
  const float* t_bq = (const float*)d_in[18];
  const float* t_bk = (const float*)d_in[19];
  const float* t_bv = (const float*)d_in[20];
  const float* t_bo = (const float*)d_in[21];
  const float* t_lng = (const float*)d_in[22];
  const float* t_lnb = (const float*)d_in[23];
  const float* f_w1 = (const float*)d_in[24];
  const float* f_b1 = (const float*)d_in[25];
  const float* f_w2 = (const float*)d_in[26];
  const float* f_b2 = (const float*)d_in[27];
  const float* f_lng = (const float*)d_in[28];
  const float* f_lnb = (const float*)d_in[29];
  const float* h_lng = (const float*)d_in[30];
  const float* h_lnb = (const float*)d_in[31];
  const float* h_w = (const float*)d_in[32];
  const float* h_b = (const float*)d_in[33];

  char* ws = (char*)d_ws;
  size_t off = 0;
  auto alloc = [&](size_t bytes) { size_t o = off; off += (bytes + 255) & ~(size_t)255; return o; };
  f16* sqkvT = (f16*)(ws + alloc((size_t)6 * 1536 * 512 * 2));
  f16* swoT  = (f16*)(ws + alloc((size_t)6 * 512 * 512 * 2));
  f16* tqkvT = (f16*)(ws + alloc((size_t)6 * 1536 * 512 * 2));
  f16* twoT  = (f16*)(ws + alloc((size_t)6 * 512 * 512 * 2));
  f16* w1T   = (f16*)(ws + alloc((size_t)6 * 2048 * 512 * 2));
  f16* w2T   = (f16*)(ws + alloc((size_t)6 * 512 * 2048 * 2));
  f16* wpT   = (f16*)(ws + alloc((size_t)512 * 768 * 2));
  float* bqkv = (float*)(ws + alloc((size_t)2 * 6 * 1536 * 4));
  f16* xh    = (f16*)(ws + alloc((size_t)NTOK * EDIM * 2));
  char* regC = ws + alloc((size_t)NTOK * 1536 * 2);   // qkv | rbufH (phase-disjoint)
  char* regD = ws + alloc((size_t)NTOK * 2048 * 2);   // P | o | h1 (phase-disjoint)
  f16* qkv   = (f16*)regC;
  f16* rbufH = (f16*)regC;
  f16* Pmat  = (f16*)regD;
  f16* obuf  = (f16*)regD;
  f16* h1    = (f16*)regD;

  dim3 tb(32, 8);
  for (int pre = 0; pre < 2; pre++) {
    const float* const* wsrc = pre ? t_w : s_w;
    f16* qdst = pre ? tqkvT : sqkvT;
    f16* odst = pre ? twoT : swoT;
    for (int wi = 0; wi < 3; wi++)
      k_transpose<<<dim3(16, 16, 6), tb, 0, stream>>>(wsrc[wi], qdst + wi * 512 * 512,
                                                      512, 512, 262144L, 786432L);
    k_transpose<<<dim3(16, 16, 6), tb, 0, stream>>>(wsrc[3], odst, 512, 512, 262144L, 262144L);
  }
  k_transpose<<<dim3(64, 16, 6), tb, 0, stream>>>(f_w1, w1T, 512, 2048, 1048576L, 1048576L);
  k_transpose<<<dim3(16, 64, 6), tb, 0, stream>>>(f_w2, w2T, 2048, 512, 1048576L, 1048576L);
  k_transpose<<<dim3(16, 24, 1), tb, 0, stream>>>(w_patch, wpT, 768, 512, 0L, 0L);
  k_pack_bias<<<72, 256, 0, stream>>>(s_bq, s_bk, s_bv, t_bq, t_bk, t_bv, bqkv);

  k_patchify<<<6144, 256, 0, stream>>>(frames, Pmat);
  // grids: all 1D, count % 8 == 0 (bijective XCD swizzle requirement)
  k_gemm<0, 0, 1><<<512, 256, 0, stream>>>(
      Pmat, wpT, b_patch, nullptr, pos, xh, 512, 768, 4);

  float* out = (float*)d_out;
  float* xf_final = out + 64512;   // second output: x fp32, written by final LN

  for (int l = 0; l < 6; l++) {
    // ---- spatial attention ----
    k_gemm<0, 0, 0><<<1536, 256, 0, stream>>>(
        xh, sqkvT + (size_t)l * 1536 * 512, bqkv + l * 1536,
        nullptr, nullptr, qkv, 1536, 512, 12);
    k_attn_spatial<<<8192, 64, 0, stream>>>(qkv, obuf);
    k_gemm<0, 1, 0><<<512, 256, 0, stream>>>(
        obuf, swoT + (size_t)l * 512 * 512, s_bo + l * 512,
        xh, nullptr, rbufH, 512, 512, 4);
    k_ln_h<0><<<NTOK / 4, 256, 0, stream>>>(rbufH, s_lng + l * 512, s_lnb + l * 512,
                                            nullptr, xh);
    // ---- temporal attention ----
    k_gemm<0, 0, 0><<<1536, 256, 0, stream>>>(
        xh, tqkvT + (size_t)l * 1536 * 512, bqkv + (6 + l) * 1536,
        nullptr, nullptr, qkv, 1536, 512, 12);
    k_attn_temporal_mfma<<<2048, 64, 0, stream>>>(qkv, obuf);
    k_gemm<0, 1, 0><<<512, 256, 0, stream>>>(
        obuf, twoT + (size_t)l * 512 * 512, t_bo + l * 512,
        xh, nullptr, rbufH, 512, 512, 4);
    k_ln_h<0><<<NTOK / 4, 256, 0, stream>>>(rbufH, t_lng + l * 512, t_lnb + l * 512,
                                            nullptr, xh);
    // ---- FFN ----
    k_gemm<1, 0, 0><<<2048, 256, 0, stream>>>(
        xh, w1T + (size_t)l * 2048 * 512, f_b1 + l * 2048,
        nullptr, nullptr, h1, 2048, 512, 16);
    k_gemm<0, 1, 0><<<512, 256, 0, stream>>>(
        h1, w2T + (size_t)l * 512 * 2048, f_b2 + l * 512,
        xh, nullptr, rbufH, 512, 2048, 4);
    if (l == 5) {
      k_ln_h<1><<<NTOK / 4, 256, 0, stream>>>(rbufH, f_lng + l * 512, f_lnb + l * 512,
                                              xf_final, nullptr);
    } else {
      k_ln_h<0><<<NTOK / 4, 256, 0, stream>>>(rbufH, f_lng + l * 512, f_lnb + l * 512,
                                              nullptr, xh);
    }
  }

  k_head<<<1008, 256, 0, stream>>>(xf_final, h_lng, h_lnb, h_w, h_b, out);
}